// Round 1
// baseline (8585.686 us; speedup 1.0000x reference)
//
#include <hip/hip_runtime.h>

// ---------------------------------------------------------------------------
// DecoderRNN: 256-step LSTM(3) + Bahdanau attention + MLP head, batch=1.
// Persistent 32-WG kernel, 4 grid barriers/step, precomputed X1/VB, WG0 MLP tail.
// ---------------------------------------------------------------------------

#define HD     256
#define SEQ    1024
#define VOCAB  47
#define NSTEP  256
#define NWG    32

// workspace layout (float offsets)
#define F_H0    64                       // [2][256] double-buffered states
#define F_C0    (F_H0 + 512)
#define F_H1    (F_C0 + 512)
#define F_C1    (F_H1 + 512)
#define F_H2    (F_C1 + 512)
#define F_C2    (F_H2 + 512)
#define F_SUMEP (F_C2 + 512)             // [32]
#define F_CTXP  (F_SUMEP + 32)           // [32][256]
#define F_X1    16384                    // [256][1024]  precomputed input gates L1
#define F_VB    (F_X1 + NSTEP*1024)      // [1024][256]  att_V@encT + att_b
#define F_W1T   (F_VB + SEQ*HD)          // [512][256]
#define F_W2T   (F_W1T + 512*256)        // [256][256]
#define F_W3T   (F_W2T + 256*256)        // [256][47]
#define F_AWT   (F_W3T + 256*VOCAB)      // [256][256]  att_W transposed

__device__ __forceinline__ float fma4(float4 w, float4 h, float acc) {
    acc = fmaf(w.x, h.x, acc); acc = fmaf(w.y, h.y, acc);
    acc = fmaf(w.z, h.z, acc); acc = fmaf(w.w, h.w, acc);
    return acc;
}
__device__ __forceinline__ float sigm(float x) {
    return __builtin_amdgcn_rcpf(1.f + __expf(-x));
}
__device__ __forceinline__ float tanh_(float x) {
    float e = __expf(2.f * x);
    return 1.f - 2.f * __builtin_amdgcn_rcpf(e + 1.f);
}

// monotonic-counter grid barrier (agent scope), NWG workgroups
__device__ __forceinline__ void gridbar(unsigned* bar, unsigned& target) {
    __syncthreads();
    target += NWG;
    if (threadIdx.x == 0) {
        __builtin_amdgcn_fence(__ATOMIC_RELEASE, "agent");
        __hip_atomic_fetch_add(bar, 1u, __ATOMIC_RELAXED, __HIP_MEMORY_SCOPE_AGENT);
        while (__hip_atomic_load(bar, __ATOMIC_RELAXED, __HIP_MEMORY_SCOPE_AGENT) < target)
            __builtin_amdgcn_s_sleep(1);
        __builtin_amdgcn_fence(__ATOMIC_ACQUIRE, "agent");
    }
    __syncthreads();
}

// OUT[r*C + c] = bias1[c] (+bias2[c]) + dot(Arow[r], Brow[c]), K=256.
// Arow[r] = Arows[idx? idx[r] : r].  grid: (R/16, C/64), block 256.
__global__ __launch_bounds__(256) void rowdot_kernel(
    const float* __restrict__ Arows, const int* __restrict__ idx,
    const float* __restrict__ Brows, const float* __restrict__ bias1,
    const float* __restrict__ bias2, float* __restrict__ out, int C)
{
    __shared__ __align__(16) float sA[16][260];
    const int tid = threadIdx.x;
    const int rl = tid >> 4, l = tid & 15;
    const int r = blockIdx.x * 16 + rl;
    const int cb = blockIdx.y * 64;
    const int arow = idx ? idx[r] : r;
    const float* Ap = Arows + arow * 256;
#pragma unroll
    for (int q = 0; q < 4; ++q)
        *(float4*)(&sA[rl][l * 16 + 4 * q]) = *(const float4*)(Ap + l * 16 + 4 * q);
    __syncthreads();
    for (int cc = 0; cc < 64; ++cc) {
        const int c = cb + cc;
        const float* Bp = Brows + c * 256;
        float acc = 0.f;
#pragma unroll
        for (int q = 0; q < 4; ++q) {
            float4 b = *(const float4*)(Bp + l * 4 + 64 * q);
            float4 a = *(const float4*)(&sA[rl][l * 4 + 64 * q]);
            acc = fma4(b, a, acc);
        }
        acc += __shfl_xor(acc, 1); acc += __shfl_xor(acc, 2);
        acc += __shfl_xor(acc, 4); acc += __shfl_xor(acc, 8);
        if (l == 0) {
            float bb = bias1[c] + (bias2 ? bias2[c] : 0.f);
            out[(size_t)r * C + c] = acc + bb;
        }
    }
}

// out[c*rows + r] = in[r*cols + c]; block (32,8); grid ((cols+31)/32,(rows+31)/32)
__global__ __launch_bounds__(256) void transpose_kernel(
    const float* __restrict__ in, float* __restrict__ out, int rows, int cols)
{
    __shared__ float tile[32][33];
    const int tx = threadIdx.x, ty = threadIdx.y;
    const int bx = blockIdx.x * 32, by = blockIdx.y * 32;
    int x = bx + tx;
#pragma unroll
    for (int j = ty; j < 32; j += 8) {
        int y = by + j;
        if (x < cols && y < rows) tile[j][tx] = in[y * cols + x];
    }
    __syncthreads();
    x = by + tx;
#pragma unroll
    for (int j = ty; j < 32; j += 8) {
        int y = bx + j;
        if (x < rows && y < cols) out[y * rows + x] = tile[tx][j];
    }
}

__global__ __launch_bounds__(256) void init_kernel(
    const float* __restrict__ h, const float* __restrict__ c, float* __restrict__ wsf)
{
    const int tid = threadIdx.x;
    if (tid == 0) *((unsigned*)wsf) = 0u;   // grid-barrier counter
    wsf[F_H0 + tid] = h[tid];        wsf[F_C0 + tid] = c[tid];
    wsf[F_H1 + tid] = h[256 + tid];  wsf[F_C1 + tid] = c[256 + tid];
    wsf[F_H2 + tid] = h[512 + tid];  wsf[F_C2 + tid] = c[512 + tid];
}

__global__ __launch_bounds__(256) void decoder_main(
    const float* __restrict__ Whh1,
    const float* __restrict__ Wih2, const float* __restrict__ Whh2,
    const float* __restrict__ Wih3, const float* __restrict__ Whh3,
    const float* __restrict__ bih2, const float* __restrict__ bhh2,
    const float* __restrict__ bih3, const float* __restrict__ bhh3,
    const float* __restrict__ av,   const float* __restrict__ enc,
    const float* __restrict__ b1,   const float* __restrict__ b2,
    const float* __restrict__ b3,
    float* __restrict__ wsf, float* __restrict__ out)
{
    __shared__ __align__(16) float sh[1056];
    const int tid = threadIdx.x;
    const int wg  = blockIdx.x;
    const int wlane = tid & 63;
    const int wv = tid >> 6;
    const int gw = wg * 4 + wv;           // global wave 0..127
    const int g8 = wlane >> 3, l8 = wlane & 7;
    const int gate = g8 & 3, usel = g8 >> 2;
    const int u  = gw * 2 + usel;         // unit 0..255
    const int ju = gate * 256 + u;        // gate row 0..1023

    unsigned* bar = (unsigned*)wsf;
    unsigned bk = 0;

    float* H0 = wsf + F_H0; float* C0 = wsf + F_C0;
    float* H1 = wsf + F_H1; float* C1 = wsf + F_C1;
    float* H2 = wsf + F_H2; float* C2 = wsf + F_C2;
    float* SUMEP = wsf + F_SUMEP; float* CTXP = wsf + F_CTXP;
    const float* X1  = wsf + F_X1;  const float* VB  = wsf + F_VB;
    const float* W1T = wsf + F_W1T; const float* W2T = wsf + F_W2T;
    const float* W3T = wsf + F_W3T; const float* AWT = wsf + F_AWT;

    sh[768 + tid] = av[tid];   // persistent att_vector in LDS [768,1024)

    for (int t = 0; t < NSTEP; ++t) {
        const int cur = (t & 1) * 256, nxt = 256 - cur;

        // ---------- P1: LSTM layer 1 (recurrent part; input part in X1) ----
        {
            sh[tid] = H0[cur + tid];
            __syncthreads();
            const float4* wr = (const float4*)(Whh1 + ju * 256);
            const float4* a4 = (const float4*)sh;
            float acc = (l8 == 0) ? X1[t * 1024 + ju] : 0.f;
#pragma unroll
            for (int m = 0; m < 8; ++m) acc = fma4(wr[l8 + 8 * m], a4[l8 + 8 * m], acc);
            acc += __shfl_xor(acc, 1); acc += __shfl_xor(acc, 2); acc += __shfl_xor(acc, 4);
            float gf = __shfl(acc, (wlane & 32) + 8);
            float gg = __shfl(acc, (wlane & 32) + 16);
            float go = __shfl(acc, (wlane & 32) + 24);
            if ((wlane & 31) == 0) {
                float cn = sigm(gf) * C0[cur + u] + sigm(acc) * tanh_(gg);
                C0[nxt + u] = cn;
                H0[nxt + u] = sigm(go) * tanh_(cn);
            }
        }
        gridbar(bar, bk);

        // ---------- P2: LSTM layer 2 ---------------------------------------
        {
            sh[tid] = H0[nxt + tid];
            sh[256 + tid] = H1[cur + tid];
            __syncthreads();
            const float4* wi = (const float4*)(Wih2 + ju * 256);
            const float4* wh = (const float4*)(Whh2 + ju * 256);
            const float4* a4 = (const float4*)sh;
            float acc = (l8 == 0) ? (bih2[ju] + bhh2[ju]) : 0.f;
#pragma unroll
            for (int m = 0; m < 8; ++m) acc = fma4(wi[l8 + 8 * m], a4[l8 + 8 * m], acc);
#pragma unroll
            for (int m = 0; m < 8; ++m) acc = fma4(wh[l8 + 8 * m], a4[64 + l8 + 8 * m], acc);
            acc += __shfl_xor(acc, 1); acc += __shfl_xor(acc, 2); acc += __shfl_xor(acc, 4);
            float gf = __shfl(acc, (wlane & 32) + 8);
            float gg = __shfl(acc, (wlane & 32) + 16);
            float go = __shfl(acc, (wlane & 32) + 24);
            if ((wlane & 31) == 0) {
                float cn = sigm(gf) * C1[cur + u] + sigm(acc) * tanh_(gg);
                C1[nxt + u] = cn;
                H1[nxt + u] = sigm(go) * tanh_(cn);
            }
        }
        gridbar(bar, bk);

        // ---------- P3: LSTM layer 3 ---------------------------------------
        {
            sh[tid] = H1[nxt + tid];
            sh[256 + tid] = H2[cur + tid];
            __syncthreads();
            const float4* wi = (const float4*)(Wih3 + ju * 256);
            const float4* wh = (const float4*)(Whh3 + ju * 256);
            const float4* a4 = (const float4*)sh;
            float acc = (l8 == 0) ? (bih3[ju] + bhh3[ju]) : 0.f;
#pragma unroll
            for (int m = 0; m < 8; ++m) acc = fma4(wi[l8 + 8 * m], a4[l8 + 8 * m], acc);
#pragma unroll
            for (int m = 0; m < 8; ++m) acc = fma4(wh[l8 + 8 * m], a4[64 + l8 + 8 * m], acc);
            acc += __shfl_xor(acc, 1); acc += __shfl_xor(acc, 2); acc += __shfl_xor(acc, 4);
            float gf = __shfl(acc, (wlane & 32) + 8);
            float gg = __shfl(acc, (wlane & 32) + 16);
            float go = __shfl(acc, (wlane & 32) + 24);
            if ((wlane & 31) == 0) {
                float cn = sigm(gf) * C2[cur + u] + sigm(acc) * tanh_(gg);
                C2[nxt + u] = cn;
                H2[nxt + u] = sigm(go) * tanh_(cn);
            }
        }
        gridbar(bar, bk);

        // ---------- P4: attention: WS (redundant per WG), e, exp, ctx partials
        {
            sh[tid] = H2[nxt + tid];
            __syncthreads();
            // WS[tid] = att_W[tid,:] . h2   (transposed weights -> coalesced)
            float w0 = 0.f, w1a = 0.f, w2a = 0.f, w3a = 0.f;
#pragma unroll 4
            for (int k = 0; k < 256; k += 4) {
                w0  = fmaf(AWT[(k + 0) * 256 + tid], sh[k + 0], w0);
                w1a = fmaf(AWT[(k + 1) * 256 + tid], sh[k + 1], w1a);
                w2a = fmaf(AWT[(k + 2) * 256 + tid], sh[k + 2], w2a);
                w3a = fmaf(AWT[(k + 3) * 256 + tid], sh[k + 3], w3a);
            }
            float wsv = (w0 + w1a) + (w2a + w3a);
            __syncthreads();
            sh[tid] = wsv;                 // WS now at sh[0:256]
            __syncthreads();
            const int sl = tid >> 3;
            const int s = wg * 32 + sl;
            const float4* vb4 = (const float4*)(VB + s * 256);
            const float4* a4 = (const float4*)sh;
            float e = 0.f;
#pragma unroll
            for (int m = 0; m < 8; ++m) {
                float4 vb = vb4[l8 + 8 * m];
                float4 w  = a4[l8 + 8 * m];        // WS
                float4 a  = a4[192 + l8 + 8 * m];  // av (floats 768..1023)
                e = fmaf(a.x, tanh_(w.x + vb.x), e);
                e = fmaf(a.y, tanh_(w.y + vb.y), e);
                e = fmaf(a.z, tanh_(w.z + vb.z), e);
                e = fmaf(a.w, tanh_(w.w + vb.w), e);
            }
            e += __shfl_xor(e, 1); e += __shfl_xor(e, 2); e += __shfl_xor(e, 4);
            if (l8 == 0) sh[512 + sl] = __expf(e);   // |e| <= ~10: no max-shift needed
            __syncthreads();
            if (tid < 32) {
                float v = sh[512 + tid];
                v += __shfl_xor(v, 16); v += __shfl_xor(v, 8); v += __shfl_xor(v, 4);
                v += __shfl_xor(v, 2);  v += __shfl_xor(v, 1);
                if (tid == 0) SUMEP[wg] = v;
            }
            float ca = 0.f;
#pragma unroll 4
            for (int q = 0; q < 32; ++q)
                ca = fmaf(sh[512 + q], enc[(wg * 32 + q) * 256 + tid], ca);
            CTXP[wg * 256 + tid] = ca;
        }
        gridbar(bar, bk);

        // ---------- tail: WG0 alone does ctx-reduce + MLP1/2/3 + out -------
        if (wg == 0) {
            float sm = 0.f;
#pragma unroll
            for (int b = 0; b < NWG; ++b) sm += SUMEP[b];
            float ca = 0.f;
#pragma unroll 4
            for (int b = 0; b < NWG; ++b) ca += CTXP[b * 256 + tid];
            sh[tid] = H2[nxt + tid];                       // cat[0:256]  = h2
            sh[256 + tid] = ca * __builtin_amdgcn_rcpf(sm);// cat[256:512]= context
            __syncthreads();
            float m0 = 0.f, m1 = 0.f, m2 = 0.f, m3 = 0.f;
#pragma unroll 4
            for (int k = 0; k < 512; k += 4) {
                m0 = fmaf(W1T[(k + 0) * 256 + tid], sh[k + 0], m0);
                m1 = fmaf(W1T[(k + 1) * 256 + tid], sh[k + 1], m1);
                m2 = fmaf(W1T[(k + 2) * 256 + tid], sh[k + 2], m2);
                m3 = fmaf(W1T[(k + 3) * 256 + tid], sh[k + 3], m3);
            }
            float v1 = fmaxf(b1[tid] + (m0 + m1) + (m2 + m3), 0.f);
            sh[512 + tid] = v1;
            __syncthreads();
            m0 = m1 = m2 = m3 = 0.f;
#pragma unroll 4
            for (int k = 0; k < 256; k += 4) {
                m0 = fmaf(W2T[(k + 0) * 256 + tid], sh[512 + k + 0], m0);
                m1 = fmaf(W2T[(k + 1) * 256 + tid], sh[512 + k + 1], m1);
                m2 = fmaf(W2T[(k + 2) * 256 + tid], sh[512 + k + 2], m2);
                m3 = fmaf(W2T[(k + 3) * 256 + tid], sh[512 + k + 3], m3);
            }
            float v2 = fmaxf(b2[tid] + (m0 + m1) + (m2 + m3), 0.f);
            __syncthreads();
            sh[tid] = v2;
            __syncthreads();
            if (tid < VOCAB) {
                m0 = m1 = m2 = m3 = 0.f;
#pragma unroll 4
                for (int k = 0; k < 256; k += 4) {
                    m0 = fmaf(W3T[(k + 0) * VOCAB + tid], sh[k + 0], m0);
                    m1 = fmaf(W3T[(k + 1) * VOCAB + tid], sh[k + 1], m1);
                    m2 = fmaf(W3T[(k + 2) * VOCAB + tid], sh[k + 2], m2);
                    m3 = fmaf(W3T[(k + 3) * VOCAB + tid], sh[k + 3], m3);
                }
                out[t * VOCAB + tid] = b3[tid] + (m0 + m1) + (m2 + m3);
            }
            __syncthreads();   // protect sh before next step's P1 staging
        }
    }
}

extern "C" void kernel_launch(void* const* d_in, const int* in_sizes, int n_in,
                              void* d_out, int out_size, void* d_ws, size_t ws_size,
                              hipStream_t stream)
{
    (void)in_sizes; (void)n_in; (void)out_size; (void)ws_size;
    const int*   Y    = (const int*)  d_in[0];
    const float* h    = (const float*)d_in[1];
    const float* c    = (const float*)d_in[2];
    const float* enc  = (const float*)d_in[3];
    const float* emb  = (const float*)d_in[4];
    const float* Wih1 = (const float*)d_in[5];
    const float* Whh1 = (const float*)d_in[6];
    const float* bih1 = (const float*)d_in[7];
    const float* bhh1 = (const float*)d_in[8];
    const float* Wih2 = (const float*)d_in[9];
    const float* Whh2 = (const float*)d_in[10];
    const float* bih2 = (const float*)d_in[11];
    const float* bhh2 = (const float*)d_in[12];
    const float* Wih3 = (const float*)d_in[13];
    const float* Whh3 = (const float*)d_in[14];
    const float* bih3 = (const float*)d_in[15];
    const float* bhh3 = (const float*)d_in[16];
    const float* av   = (const float*)d_in[17];
    const float* attW = (const float*)d_in[18];
    const float* attV = (const float*)d_in[19];
    const float* attB = (const float*)d_in[20];
    const float* w1   = (const float*)d_in[21];
    const float* b1   = (const float*)d_in[22];
    const float* w2   = (const float*)d_in[23];
    const float* b2   = (const float*)d_in[24];
    const float* w3   = (const float*)d_in[25];
    const float* b3   = (const float*)d_in[26];
    float* wsf = (float*)d_ws;
    float* out = (float*)d_out;

    // prologue (parallel, loop-invariant)
    rowdot_kernel<<<dim3(16, 16), 256, 0, stream>>>(emb, Y, Wih1, bih1, bhh1, wsf + F_X1, 1024);
    rowdot_kernel<<<dim3(64, 4),  256, 0, stream>>>(enc, nullptr, attV, attB, nullptr, wsf + F_VB, 256);
    transpose_kernel<<<dim3(16, 8), dim3(32, 8), 0, stream>>>(w1,   wsf + F_W1T, 256, 512);
    transpose_kernel<<<dim3(8, 8),  dim3(32, 8), 0, stream>>>(w2,   wsf + F_W2T, 256, 256);
    transpose_kernel<<<dim3(8, 2),  dim3(32, 8), 0, stream>>>(w3,   wsf + F_W3T, 47, 256);
    transpose_kernel<<<dim3(8, 8),  dim3(32, 8), 0, stream>>>(attW, wsf + F_AWT, 256, 256);
    init_kernel<<<1, 256, 0, stream>>>(h, c, wsf);

    // persistent 256-step decoder
    decoder_main<<<NWG, 256, 0, stream>>>(Whh1, Wih2, Whh2, Wih3, Whh3,
                                          bih2, bhh2, bih3, bhh3,
                                          av, enc, b1, b2, b3, wsf, out);
}

// Round 2
// 1340.555 us; speedup vs baseline: 6.4046x; 6.4046x over previous
//
#include <hip/hip_runtime.h>

// ---------------------------------------------------------------------------
// DecoderRNN: 256-step LSTM(3) + Bahdanau attention + MLP head, batch=1.
// Round 2: diagonally-pipelined recurrence (1 grid barrier/slot, 258 slots,
// weights in VGPRs, c-state in registers), then batch-parallel attention+MLP
// over all 256 steps in separate kernels.
// ---------------------------------------------------------------------------

#define HD     256
#define SEQ    1024
#define VOCAB  47
#define NSTEP  256
#define NWGR   40      // recurrence workgroups: 8 (L1) + 16 (L2) + 16 (L3)

// workspace layout (float offsets)
#define F_BAR   0
#define F_SUMEP 64                        // [256][16] per-(t, s-tile) exp sums
#define F_H0R   (F_SUMEP + 4096)          // [4][256] h0 ring (row (t+1)&3)
#define F_H1R   (F_H0R + 1024)            // [4][256] h1 ring
#define F_H2A   (F_H1R + 1024)            // [257][256] all h2 states (row t+1)
#define F_WS    (F_H2A + 65792)           // [256][256] att_W @ h2[t]
#define F_CTX   (F_WS + 65536)            // [256][256] unnormalized context
#define F_O1    (F_CTX + 65536)           // [256][256] mlp1 out
#define F_O2    (F_O1 + 65536)            // [256][256] mlp2 out
#define F_X1    (F_O2 + 65536)            // [256][1024] precomputed L1 input gates
#define F_EXPE  F_X1                      // [256][1024] overlays X1 (X1 dead by then)
#define F_VB    (F_X1 + 262144)           // [1024][256] att_V@encT + att_b
#define F_W1T   (F_VB + 262144)           // [512][256]
#define F_W2T   (F_W1T + 131072)          // [256][256]
#define F_W3T   (F_W2T + 65536)           // [256][47]
#define F_AWT   (F_W3T + 12032)           // [256][256] att_W transposed

__device__ __forceinline__ float fma4(float4 w, float4 h, float acc) {
    acc = fmaf(w.x, h.x, acc); acc = fmaf(w.y, h.y, acc);
    acc = fmaf(w.z, h.z, acc); acc = fmaf(w.w, h.w, acc);
    return acc;
}
__device__ __forceinline__ float sigm(float x) {
    return __builtin_amdgcn_rcpf(1.f + __expf(-x));
}
__device__ __forceinline__ float tanh_(float x) {
    float e = __expf(2.f * x);
    return 1.f - 2.f * __builtin_amdgcn_rcpf(e + 1.f);
}

// monotonic-counter grid barrier (agent scope), NWGR workgroups
__device__ __forceinline__ void gridbar(unsigned* bar, unsigned& target) {
    __syncthreads();
    target += NWGR;
    if (threadIdx.x == 0) {
        __builtin_amdgcn_fence(__ATOMIC_RELEASE, "agent");
        __hip_atomic_fetch_add(bar, 1u, __ATOMIC_RELAXED, __HIP_MEMORY_SCOPE_AGENT);
        while (__hip_atomic_load(bar, __ATOMIC_RELAXED, __HIP_MEMORY_SCOPE_AGENT) < target)
            __builtin_amdgcn_s_sleep(1);
        __builtin_amdgcn_fence(__ATOMIC_ACQUIRE, "agent");
    }
    __syncthreads();
}

// OUT[r*C + c] = bias1[c] (+bias2[c]) + dot(Arows[idx?idx[r]:r], Brows[c]), K=256.
__global__ __launch_bounds__(256) void rowdot_kernel(
    const float* __restrict__ Arows, const int* __restrict__ idx,
    const float* __restrict__ Brows, const float* __restrict__ bias1,
    const float* __restrict__ bias2, float* __restrict__ out, int C)
{
    __shared__ __align__(16) float sA[16][260];
    const int tid = threadIdx.x;
    const int rl = tid >> 4, l = tid & 15;
    const int r = blockIdx.x * 16 + rl;
    const int cb = blockIdx.y * 64;
    const int arow = idx ? idx[r] : r;
    const float* Ap = Arows + arow * 256;
#pragma unroll
    for (int q = 0; q < 4; ++q)
        *(float4*)(&sA[rl][l * 16 + 4 * q]) = *(const float4*)(Ap + l * 16 + 4 * q);
    __syncthreads();
    for (int cc = 0; cc < 64; ++cc) {
        const int c = cb + cc;
        const float* Bp = Brows + c * 256;
        float acc = 0.f;
#pragma unroll
        for (int q = 0; q < 4; ++q) {
            float4 b = *(const float4*)(Bp + l * 4 + 64 * q);
            float4 a = *(const float4*)(&sA[rl][l * 4 + 64 * q]);
            acc = fma4(b, a, acc);
        }
        acc += __shfl_xor(acc, 1); acc += __shfl_xor(acc, 2);
        acc += __shfl_xor(acc, 4); acc += __shfl_xor(acc, 8);
        if (l == 0) {
            float bb = bias1[c] + (bias2 ? bias2[c] : 0.f);
            out[(size_t)r * C + c] = acc + bb;
        }
    }
}

// out[c*rows + r] = in[r*cols + c]
__global__ __launch_bounds__(256) void transpose_kernel(
    const float* __restrict__ in, float* __restrict__ out, int rows, int cols)
{
    __shared__ float tile[32][33];
    const int tx = threadIdx.x, ty = threadIdx.y;
    const int bx = blockIdx.x * 32, by = blockIdx.y * 32;
    int x = bx + tx;
#pragma unroll
    for (int j = ty; j < 32; j += 8) {
        int y = by + j;
        if (x < cols && y < rows) tile[j][tx] = in[y * cols + x];
    }
    __syncthreads();
    x = by + tx;
#pragma unroll
    for (int j = ty; j < 32; j += 8) {
        int y = bx + j;
        if (x < rows && y < cols) out[y * rows + x] = tile[tx][j];
    }
}

__global__ __launch_bounds__(256) void init_kernel(
    const float* __restrict__ h, float* __restrict__ wsf)
{
    const int tid = threadIdx.x;
    if (tid == 0) *((unsigned*)(wsf + F_BAR)) = 0u;
    wsf[F_H0R + tid] = h[tid];          // ring row 0 = init
    wsf[F_H1R + tid] = h[256 + tid];
    wsf[F_H2A + tid] = h[512 + tid];    // row 0 = init
}

// ---------------------------------------------------------------------------
// Pipelined recurrence: slot k computes L1[t=k], L2[t=k-1], L3[t=k-2].
// WGs 0..7: L1 (4 lanes/row); WGs 8..23: L2 (8 lanes/row); WGs 24..39: L3.
// Weights hoisted to VGPRs; c-state in a register on the writer lane.
// ---------------------------------------------------------------------------
__global__ __launch_bounds__(512) void recurrence_kernel(
    const float* __restrict__ Whh1,
    const float* __restrict__ Wih2, const float* __restrict__ Whh2,
    const float* __restrict__ Wih3, const float* __restrict__ Whh3,
    const float* __restrict__ bih2, const float* __restrict__ bhh2,
    const float* __restrict__ bih3, const float* __restrict__ bhh3,
    const float* __restrict__ cin,
    float* __restrict__ wsf)
{
    __shared__ __align__(16) float sh[512];
    const int tid = threadIdx.x, wg = blockIdx.x;
    const int wave = tid >> 6, wlane = tid & 63;
    unsigned* bar = (unsigned*)(wsf + F_BAR);
    unsigned bk = 0;

    float* H0R = wsf + F_H0R;
    float* H1R = wsf + F_H1R;
    float* H2A = wsf + F_H2A;
    const float* X1 = wsf + F_X1;

    const int role = (wg < 8) ? 0 : (wg < 24 ? 1 : 2);

    float4 wA[16];
    int u, ju;
    float biasr = 0.f, creg = 0.f;

    if (role == 0) {
        const int ug = wlane >> 4, gate = (wlane >> 2) & 3, l4 = wlane & 3;
        u = wg * 32 + wave * 4 + ug;
        ju = gate * 256 + u;
        const float* wp = Whh1 + ju * 256 + l4 * 64;
#pragma unroll
        for (int m = 0; m < 16; ++m) wA[m] = *(const float4*)(wp + 4 * m);
        if ((wlane & 15) == 0) creg = cin[u];
    } else {
        const int ug = wlane >> 5, gate = (wlane >> 3) & 3, l8 = wlane & 7;
        const int wgr = wg - (role == 1 ? 8 : 24);
        u = wgr * 16 + wave * 2 + ug;
        ju = gate * 256 + u;
        const float* Wi = (role == 1) ? Wih2 : Wih3;
        const float* Wh = (role == 1) ? Whh2 : Whh3;
        const float* wip = Wi + ju * 256 + l8 * 32;
        const float* whp = Wh + ju * 256 + l8 * 32;
#pragma unroll
        for (int m = 0; m < 8; ++m) {
            wA[m]     = *(const float4*)(wip + 4 * m);
            wA[8 + m] = *(const float4*)(whp + 4 * m);
        }
        if (l8 == 0) biasr = (role == 1) ? (bih2[ju] + bhh2[ju]) : (bih3[ju] + bhh3[ju]);
        if ((wlane & 31) == 0) creg = cin[((role == 1) ? 256 : 512) + u];
    }

    for (int k = 0; k < NSTEP + 2; ++k) {
        if (k) gridbar(bar, bk);
        const int t = k - role;
        if (t < 0 || t > NSTEP - 1) continue;

        if (role == 0) {
            if (tid < 256) sh[tid] = H0R[(t & 3) * 256 + tid];
            __syncthreads();
            float acc = ((wlane & 3) == 0) ? X1[t * 1024 + ju] : 0.f;
            const float4* a4 = (const float4*)sh;
            const int base = (wlane & 3) * 16;
#pragma unroll
            for (int m = 0; m < 16; ++m) acc = fma4(wA[m], a4[base + m], acc);
            acc += __shfl_xor(acc, 1); acc += __shfl_xor(acc, 2);
            const int b16 = wlane & 48;
            float gf = __shfl(acc, b16 + 4);
            float gg = __shfl(acc, b16 + 8);
            float go = __shfl(acc, b16 + 12);
            if ((wlane & 15) == 0) {
                float cn = sigm(gf) * creg + sigm(acc) * tanh_(gg);
                creg = cn;
                H0R[(((t + 1) & 3)) * 256 + u] = sigm(go) * tanh_(cn);
            }
        } else {
            const float* Hin = (role == 1) ? H0R : H1R;   // x = h_{layer-1}[t], ring row (t+1)&3
            if (tid < 256) sh[tid] = Hin[((t + 1) & 3) * 256 + tid];
            else {
                if (role == 1) sh[tid] = H1R[(t & 3) * 256 + (tid - 256)];
                else           sh[tid] = H2A[t * 256 + (tid - 256)];
            }
            __syncthreads();
            float acc = ((wlane & 7) == 0) ? biasr : 0.f;
            const float4* a4 = (const float4*)sh;
            const int base = (wlane & 7) * 8;
#pragma unroll
            for (int m = 0; m < 8; ++m) acc = fma4(wA[m], a4[base + m], acc);
#pragma unroll
            for (int m = 0; m < 8; ++m) acc = fma4(wA[8 + m], a4[64 + base + m], acc);
            acc += __shfl_xor(acc, 1); acc += __shfl_xor(acc, 2); acc += __shfl_xor(acc, 4);
            const int b32 = wlane & 32;
            float gf = __shfl(acc, b32 + 8);
            float gg = __shfl(acc, b32 + 16);
            float go = __shfl(acc, b32 + 24);
            if ((wlane & 31) == 0) {
                float cn = sigm(gf) * creg + sigm(acc) * tanh_(gg);
                creg = cn;
                float hn = sigm(go) * tanh_(cn);
                if (role == 1) H1R[((t + 1) & 3) * 256 + u] = hn;
                else           H2A[(t + 1) * 256 + u] = hn;
            }
        }
    }
}

// WS[t][j] = sum_k att_W[j][k] h2[t][k]; also zeroes CTX rows (atomic target).
__global__ __launch_bounds__(256) void ws_kernel(float* __restrict__ wsf)
{
    const int tid = threadIdx.x;
    const int t0 = blockIdx.x * 4;
    const float* H2A = wsf + F_H2A;
    const float* AWT = wsf + F_AWT;
    float* WS  = wsf + F_WS;
    float* CTX = wsf + F_CTX;
    __shared__ float h2s[4][256];
#pragma unroll
    for (int q = 0; q < 4; ++q) {
        h2s[q][tid] = H2A[(t0 + q + 1) * 256 + tid];
        CTX[(t0 + q) * 256 + tid] = 0.f;
    }
    __syncthreads();
    float a0 = 0.f, a1 = 0.f, a2 = 0.f, a3 = 0.f;
#pragma unroll 4
    for (int k2 = 0; k2 < 256; ++k2) {
        float w = AWT[k2 * 256 + tid];
        a0 = fmaf(w, h2s[0][k2], a0); a1 = fmaf(w, h2s[1][k2], a1);
        a2 = fmaf(w, h2s[2][k2], a2); a3 = fmaf(w, h2s[3][k2], a3);
    }
    WS[(t0 + 0) * 256 + tid] = a0;
    WS[(t0 + 1) * 256 + tid] = a1;
    WS[(t0 + 2) * 256 + tid] = a2;
    WS[(t0 + 3) * 256 + tid] = a3;
}

// Per (t-tile 8, s-tile 64): e, exp(e), tile exp-sums, unnormalized ctx partials.
__global__ __launch_bounds__(256) void att_kernel(
    const float* __restrict__ av, const float* __restrict__ enc,
    float* __restrict__ wsf)
{
    const int tid = threadIdx.x;
    const int t0 = blockIdx.x * 8, s0 = blockIdx.y * 64;
    const float* VB = wsf + F_VB;
    const float* WS = wsf + F_WS;
    float* EXPE  = wsf + F_EXPE;
    float* SUMEP = wsf + F_SUMEP;
    float* CTX   = wsf + F_CTX;
    __shared__ float vbt[256][65];   // transposed VB tile [k][s], pad 65
    __shared__ float wss[8][256];
    __shared__ float avs[256];
    __shared__ float exs[8][64];
    avs[tid] = av[tid];
#pragma unroll
    for (int r = 0; r < 8; ++r) wss[r][tid] = WS[(t0 + r) * 256 + tid];
#pragma unroll 4
    for (int r = 0; r < 64; ++r) vbt[tid][r] = VB[(s0 + r) * 256 + tid];
    __syncthreads();
    const int sidx = tid & 63, tq = tid >> 6;
#pragma unroll
    for (int pass = 0; pass < 2; ++pass) {
        const int tl = tq + 4 * pass;
        float e = 0.f;
#pragma unroll 4
        for (int k2 = 0; k2 < 256; ++k2)
            e = fmaf(avs[k2], tanh_(wss[tl][k2] + vbt[k2][sidx]), e);
        float ex = __expf(e);        // |e| bounded ~10: no max-shift needed
        EXPE[(t0 + tl) * 1024 + s0 + sidx] = ex;
        exs[tl][sidx] = ex;
        float s = ex;
        s += __shfl_xor(s, 1);  s += __shfl_xor(s, 2);  s += __shfl_xor(s, 4);
        s += __shfl_xor(s, 8);  s += __shfl_xor(s, 16); s += __shfl_xor(s, 32);
        if (sidx == 0) SUMEP[(t0 + tl) * 16 + blockIdx.y] = s;
    }
    __syncthreads();
    // ctx partials over this s-tile: 64 coalesced enc loads, 8 fma each
    float ca[8] = {0.f, 0.f, 0.f, 0.f, 0.f, 0.f, 0.f, 0.f};
#pragma unroll 2
    for (int sl = 0; sl < 64; ++sl) {
        float ev = enc[(s0 + sl) * 256 + tid];
#pragma unroll
        for (int r = 0; r < 8; ++r) ca[r] = fmaf(exs[r][sl], ev, ca[r]);
    }
#pragma unroll
    for (int r = 0; r < 8; ++r)
        atomicAdd(&CTX[(t0 + r) * 256 + tid], ca[r]);
}

// O1[t][j] = relu(b1[j] + sum_k W1[j][k] cat[t][k]), cat=[h2, ctx/sum]
__global__ __launch_bounds__(256) void mlp1_kernel(
    const float* __restrict__ b1, float* __restrict__ wsf)
{
    const int tid = threadIdx.x;
    const int t0 = blockIdx.x * 4;
    const float* H2A = wsf + F_H2A;
    const float* CTX = wsf + F_CTX;
    const float* SUMEP = wsf + F_SUMEP;
    const float* W1T = wsf + F_W1T;
    float* O1 = wsf + F_O1;
    __shared__ __align__(16) float cat4[4][512];
    __shared__ float rs[4];
    if (tid < 4) {
        float s = 0.f;
#pragma unroll
        for (int i = 0; i < 16; ++i) s += SUMEP[(t0 + tid) * 16 + i];
        rs[tid] = 1.0f / s;
    }
    __syncthreads();
#pragma unroll
    for (int r = 0; r < 8; ++r) {
        int idx = r * 256 + tid;
        int tl = idx >> 9, j = idx & 511;
        cat4[tl][j] = (j < 256) ? H2A[(t0 + tl + 1) * 256 + j]
                                : CTX[(t0 + tl) * 256 + (j - 256)] * rs[tl];
    }
    __syncthreads();
    float a0 = 0.f, a1 = 0.f, a2 = 0.f, a3 = 0.f;
    float bv = b1[tid];
#pragma unroll 4
    for (int k2 = 0; k2 < 512; ++k2) {
        float w = W1T[k2 * 256 + tid];
        a0 = fmaf(w, cat4[0][k2], a0); a1 = fmaf(w, cat4[1][k2], a1);
        a2 = fmaf(w, cat4[2][k2], a2); a3 = fmaf(w, cat4[3][k2], a3);
    }
    O1[(t0 + 0) * 256 + tid] = fmaxf(bv + a0, 0.f);
    O1[(t0 + 1) * 256 + tid] = fmaxf(bv + a1, 0.f);
    O1[(t0 + 2) * 256 + tid] = fmaxf(bv + a2, 0.f);
    O1[(t0 + 3) * 256 + tid] = fmaxf(bv + a3, 0.f);
}

__global__ __launch_bounds__(256) void mlp2_kernel(
    const float* __restrict__ b2, float* __restrict__ wsf)
{
    const int tid = threadIdx.x;
    const int t0 = blockIdx.x * 4;
    const float* O1 = wsf + F_O1;
    const float* W2T = wsf + F_W2T;
    float* O2 = wsf + F_O2;
    __shared__ float v4[4][256];
#pragma unroll
    for (int q = 0; q < 4; ++q) v4[q][tid] = O1[(t0 + q) * 256 + tid];
    __syncthreads();
    float a0 = 0.f, a1 = 0.f, a2 = 0.f, a3 = 0.f;
    float bv = b2[tid];
#pragma unroll 4
    for (int k2 = 0; k2 < 256; ++k2) {
        float w = W2T[k2 * 256 + tid];
        a0 = fmaf(w, v4[0][k2], a0); a1 = fmaf(w, v4[1][k2], a1);
        a2 = fmaf(w, v4[2][k2], a2); a3 = fmaf(w, v4[3][k2], a3);
    }
    O2[(t0 + 0) * 256 + tid] = fmaxf(bv + a0, 0.f);
    O2[(t0 + 1) * 256 + tid] = fmaxf(bv + a1, 0.f);
    O2[(t0 + 2) * 256 + tid] = fmaxf(bv + a2, 0.f);
    O2[(t0 + 3) * 256 + tid] = fmaxf(bv + a3, 0.f);
}

__global__ __launch_bounds__(256) void mlp3_kernel(
    const float* __restrict__ b3, float* __restrict__ wsf, float* __restrict__ out)
{
    const int tid = threadIdx.x;
    const int t0 = blockIdx.x * 16;
    const float* O2 = wsf + F_O2;
    const float* W3T = wsf + F_W3T;
    __shared__ float v2s[16][256];
#pragma unroll
    for (int r = 0; r < 16; ++r) v2s[r][tid] = O2[(t0 + r) * 256 + tid];
    __syncthreads();
    if (tid < VOCAB) {
        float acc[16];
#pragma unroll
        for (int q = 0; q < 16; ++q) acc[q] = 0.f;
#pragma unroll 2
        for (int k2 = 0; k2 < 256; ++k2) {
            float w = W3T[k2 * VOCAB + tid];
#pragma unroll
            for (int q = 0; q < 16; ++q) acc[q] = fmaf(w, v2s[q][k2], acc[q]);
        }
        float bv = b3[tid];
#pragma unroll
        for (int q = 0; q < 16; ++q) out[(t0 + q) * VOCAB + tid] = bv + acc[q];
    }
}

extern "C" void kernel_launch(void* const* d_in, const int* in_sizes, int n_in,
                              void* d_out, int out_size, void* d_ws, size_t ws_size,
                              hipStream_t stream)
{
    (void)in_sizes; (void)n_in; (void)out_size; (void)ws_size;
    const int*   Y    = (const int*)  d_in[0];
    const float* h    = (const float*)d_in[1];
    const float* c    = (const float*)d_in[2];
    const float* enc  = (const float*)d_in[3];
    const float* emb  = (const float*)d_in[4];
    const float* Wih1 = (const float*)d_in[5];
    const float* Whh1 = (const float*)d_in[6];
    const float* bih1 = (const float*)d_in[7];
    const float* bhh1 = (const float*)d_in[8];
    const float* Wih2 = (const float*)d_in[9];
    const float* Whh2 = (const float*)d_in[10];
    const float* bih2 = (const float*)d_in[11];
    const float* bhh2 = (const float*)d_in[12];
    const float* Wih3 = (const float*)d_in[13];
    const float* Whh3 = (const float*)d_in[14];
    const float* bih3 = (const float*)d_in[15];
    const float* bhh3 = (const float*)d_in[16];
    const float* av   = (const float*)d_in[17];
    const float* attW = (const float*)d_in[18];
    const float* attV = (const float*)d_in[19];
    const float* attB = (const float*)d_in[20];
    const float* w1   = (const float*)d_in[21];
    const float* b1   = (const float*)d_in[22];
    const float* w2   = (const float*)d_in[23];
    const float* b2   = (const float*)d_in[24];
    const float* w3   = (const float*)d_in[25];
    const float* b3   = (const float*)d_in[26];
    float* wsf = (float*)d_ws;
    float* out = (float*)d_out;

    // prologue (loop-invariant precompute)
    rowdot_kernel<<<dim3(16, 16), 256, 0, stream>>>(emb, Y, Wih1, bih1, bhh1, wsf + F_X1, 1024);
    rowdot_kernel<<<dim3(64, 4),  256, 0, stream>>>(enc, nullptr, attV, attB, nullptr, wsf + F_VB, 256);
    transpose_kernel<<<dim3(16, 8), dim3(32, 8), 0, stream>>>(w1,   wsf + F_W1T, 256, 512);
    transpose_kernel<<<dim3(8, 8),  dim3(32, 8), 0, stream>>>(w2,   wsf + F_W2T, 256, 256);
    transpose_kernel<<<dim3(8, 2),  dim3(32, 8), 0, stream>>>(w3,   wsf + F_W3T, VOCAB, 256);
    transpose_kernel<<<dim3(8, 8),  dim3(32, 8), 0, stream>>>(attW, wsf + F_AWT, 256, 256);
    init_kernel<<<1, 256, 0, stream>>>(h, wsf);

    // pipelined recurrence: 258 slots, 1 grid barrier each
    recurrence_kernel<<<NWGR, 512, 0, stream>>>(Whh1, Wih2, Whh2, Wih3, Whh3,
                                                bih2, bhh2, bih3, bhh3, c, wsf);

    // batch-parallel attention + MLP over all 256 steps
    ws_kernel<<<64, 256, 0, stream>>>(wsf);
    att_kernel<<<dim3(32, 16), 256, 0, stream>>>(av, enc, wsf);
    mlp1_kernel<<<64, 256, 0, stream>>>(b1, wsf);
    mlp2_kernel<<<64, 256, 0, stream>>>(b2, wsf);
    mlp3_kernel<<<16, 256, 0, stream>>>(b3, wsf, out);
}

// Round 3
// 896.892 us; speedup vs baseline: 9.5727x; 1.4947x over previous
//
#include <hip/hip_runtime.h>

// ---------------------------------------------------------------------------
// DecoderRNN: 256-step LSTM(3) + Bahdanau attention + MLP head, batch=1.
// Round 3: barrier-free recurrence via tagged uncached handoffs (8B atomic
// {tag,value} stores, relaxed agent scope -> IF$-coherent, no fences).
// Roles free-run; pipeline skew emerges from data availability.
// Post: t-parallel ws/att (partials, no atomics) + mlp1 + fused mlp23.
// ---------------------------------------------------------------------------

#define HD     256
#define SEQ    1024
#define VOCAB  47
#define NSTEP  256
#define NWGR   40      // recurrence workgroups: 8 (L1) + 16 (L2) + 16 (L3)

typedef unsigned long long u64;

// workspace layout (float offsets)
#define F_SUMEP 64                        // [256][8] per-(t, s-tile) exp sums
#define F_H0A   2112                      // u64 [257][256] tagged h0 history
#define F_H1A   133696                    // u64 [257][256]
#define F_H2A   265280                    // u64 [257][256]
#define F_WS    396864                    // [256][256] att_W @ h2[t]
#define F_CTXP  462400                    // [8][256][256] ctx partials per s-tile
#define F_X1    986688                    // [256][1024] precomputed L1 input gates
#define F_O1    F_X1                      // overlays X1 (dead after recurrence)
#define F_VB    1248832                   // [1024][256] att_V@encT + att_b
#define F_W1T   1510976                   // [512][256]
#define F_W2T   1642048                   // [256][256]
#define F_W3T   1707584                   // [256][47]
#define F_AWT   1719616                   // [256][256] att_W transposed

__device__ __forceinline__ float fma4(float4 w, float4 h, float acc) {
    acc = fmaf(w.x, h.x, acc); acc = fmaf(w.y, h.y, acc);
    acc = fmaf(w.z, h.z, acc); acc = fmaf(w.w, h.w, acc);
    return acc;
}
__device__ __forceinline__ float sigm(float x) {
    return __builtin_amdgcn_rcpf(1.f + __expf(-x));
}
__device__ __forceinline__ float tanh_(float x) {
    float e = __expf(2.f * x);
    return 1.f - 2.f * __builtin_amdgcn_rcpf(e + 1.f);
}

// tagged uncached handoff: 8B atom {tag | float bits}; relaxed agent scope
// compiles to sc0/sc1 (IF$-coherent) accesses -> no fences, no L2 maintenance.
__device__ __forceinline__ void tagstore(u64* p, float v, unsigned tag) {
    u64 pk = ((u64)tag << 32) | (u64)__float_as_uint(v);
    __hip_atomic_store(p, pk, __ATOMIC_RELAXED, __HIP_MEMORY_SCOPE_AGENT);
}
__device__ __forceinline__ float pollval(u64* p, unsigned tag) {
    u64 v;
    do { v = __hip_atomic_load(p, __ATOMIC_RELAXED, __HIP_MEMORY_SCOPE_AGENT); }
    while ((unsigned)(v >> 32) != tag);
    return __uint_as_float((unsigned)(v & 0xffffffffull));
}

// OUT[r*C + c] = bias1[c] (+bias2[c]) + dot(Arows[idx?idx[r]:r], Brows[c]), K=256.
__global__ __launch_bounds__(256) void rowdot_kernel(
    const float* __restrict__ Arows, const int* __restrict__ idx,
    const float* __restrict__ Brows, const float* __restrict__ bias1,
    const float* __restrict__ bias2, float* __restrict__ out, int C)
{
    __shared__ __align__(16) float sA[16][260];
    const int tid = threadIdx.x;
    const int rl = tid >> 4, l = tid & 15;
    const int r = blockIdx.x * 16 + rl;
    const int cb = blockIdx.y * 64;
    const int arow = idx ? idx[r] : r;
    const float* Ap = Arows + arow * 256;
#pragma unroll
    for (int q = 0; q < 4; ++q)
        *(float4*)(&sA[rl][l * 16 + 4 * q]) = *(const float4*)(Ap + l * 16 + 4 * q);
    __syncthreads();
    for (int cc = 0; cc < 64; ++cc) {
        const int c = cb + cc;
        const float* Bp = Brows + c * 256;
        float acc = 0.f;
#pragma unroll
        for (int q = 0; q < 4; ++q) {
            float4 b = *(const float4*)(Bp + l * 4 + 64 * q);
            float4 a = *(const float4*)(&sA[rl][l * 4 + 64 * q]);
            acc = fma4(b, a, acc);
        }
        acc += __shfl_xor(acc, 1); acc += __shfl_xor(acc, 2);
        acc += __shfl_xor(acc, 4); acc += __shfl_xor(acc, 8);
        if (l == 0) {
            float bb = bias1[c] + (bias2 ? bias2[c] : 0.f);
            out[(size_t)r * C + c] = acc + bb;
        }
    }
}

// out[c*rows + r] = in[r*cols + c]
__global__ __launch_bounds__(256) void transpose_kernel(
    const float* __restrict__ in, float* __restrict__ out, int rows, int cols)
{
    __shared__ float tile[32][33];
    const int tx = threadIdx.x, ty = threadIdx.y;
    const int bx = blockIdx.x * 32, by = blockIdx.y * 32;
    int x = bx + tx;
#pragma unroll
    for (int j = ty; j < 32; j += 8) {
        int y = by + j;
        if (x < cols && y < rows) tile[j][tx] = in[y * cols + x];
    }
    __syncthreads();
    x = by + tx;
#pragma unroll
    for (int j = ty; j < 32; j += 8) {
        int y = bx + j;
        if (x < rows && y < cols) out[y * rows + x] = tile[tx][j];
    }
}

__global__ __launch_bounds__(256) void init_kernel(
    const float* __restrict__ h, float* __restrict__ wsf)
{
    const int tid = threadIdx.x;
    // row 0 = initial states, tag 1; tagged stores so IF$ holds them (pollers bypass L2)
    tagstore((u64*)(wsf + F_H0A) + tid, h[tid],       1u);
    tagstore((u64*)(wsf + F_H1A) + tid, h[256 + tid], 1u);
    tagstore((u64*)(wsf + F_H2A) + tid, h[512 + tid], 1u);
}

// ---------------------------------------------------------------------------
// Barrier-free recurrence. WGs 0..7: L1; 8..23: L2; 24..39: L3.
// Weights hoisted to VGPRs; c-state in registers; h handoff via tagged atoms.
// ---------------------------------------------------------------------------
__global__ __launch_bounds__(512) void recurrence_kernel(
    const float* __restrict__ Whh1,
    const float* __restrict__ Wih2, const float* __restrict__ Whh2,
    const float* __restrict__ Wih3, const float* __restrict__ Whh3,
    const float* __restrict__ bih2, const float* __restrict__ bhh2,
    const float* __restrict__ bih3, const float* __restrict__ bhh3,
    const float* __restrict__ cin,
    float* __restrict__ wsf)
{
    __shared__ __align__(16) float sh[512];
    const int tid = threadIdx.x, wg = blockIdx.x;
    const int wave = tid >> 6, wlane = tid & 63;

    u64* H0A = (u64*)(wsf + F_H0A);
    u64* H1A = (u64*)(wsf + F_H1A);
    u64* H2A = (u64*)(wsf + F_H2A);
    const float* X1 = wsf + F_X1;

    const int role = (wg < 8) ? 0 : (wg < 24 ? 1 : 2);

    if (role == 0) {
        const int ug = wlane >> 4, gate = (wlane >> 2) & 3, l4 = wlane & 3;
        const int u = wg * 32 + wave * 4 + ug;
        const int ju = gate * 256 + u;
        float4 wA[16];
        const float* wp = Whh1 + ju * 256 + l4 * 64;
#pragma unroll
        for (int m = 0; m < 16; ++m) wA[m] = *(const float4*)(wp + 4 * m);
        float creg = ((wlane & 15) == 0) ? cin[u] : 0.f;
        const int base = l4 * 16, b16 = wlane & 48;

        for (int t = 0; t < NSTEP; ++t) {
            float x1v = (l4 == 0) ? X1[t * 1024 + ju] : 0.f;
            if (tid < 256) sh[tid] = pollval(H0A + t * 256 + tid, t + 1);
            __syncthreads();
            float acc = x1v;
            const float4* a4 = (const float4*)sh;
#pragma unroll
            for (int m = 0; m < 16; ++m) acc = fma4(wA[m], a4[base + m], acc);
            acc += __shfl_xor(acc, 1); acc += __shfl_xor(acc, 2);
            float gf = __shfl(acc, b16 + 4);
            float gg = __shfl(acc, b16 + 8);
            float go = __shfl(acc, b16 + 12);
            if ((wlane & 15) == 0) {
                float cn = sigm(gf) * creg + sigm(acc) * tanh_(gg);
                creg = cn;
                tagstore(H0A + (t + 1) * 256 + u, sigm(go) * tanh_(cn), t + 2);
            }
            __syncthreads();
        }
    } else {
        const int ug = wlane >> 5, gate = (wlane >> 3) & 3, l8 = wlane & 7;
        const int wgr = wg - (role == 1 ? 8 : 24);
        const int u = wgr * 16 + wave * 2 + ug;
        const int ju = gate * 256 + u;
        const float* Wi = (role == 1) ? Wih2 : Wih3;
        const float* Wh = (role == 1) ? Whh2 : Whh3;
        float4 wA[16];
        const float* wip = Wi + ju * 256 + l8 * 32;
        const float* whp = Wh + ju * 256 + l8 * 32;
#pragma unroll
        for (int m = 0; m < 8; ++m) {
            wA[m]     = *(const float4*)(wip + 4 * m);
            wA[8 + m] = *(const float4*)(whp + 4 * m);
        }
        float biasr = (l8 == 0)
            ? ((role == 1) ? (bih2[ju] + bhh2[ju]) : (bih3[ju] + bhh3[ju])) : 0.f;
        float creg = ((wlane & 31) == 0) ? cin[((role == 1) ? 256 : 512) + u] : 0.f;
        u64* Hx   = (role == 1) ? H0A : H1A;   // upstream layer's h
        u64* Hown = (role == 1) ? H1A : H2A;   // this layer's h
        const int base = l8 * 8, b32 = wlane & 32;

        for (int t = 0; t < NSTEP; ++t) {
            if (tid < 256) sh[tid] = pollval(Hx + (t + 1) * 256 + tid, t + 2);
            else           sh[tid] = pollval(Hown + t * 256 + (tid - 256), t + 1);
            __syncthreads();
            float acc = biasr;
            const float4* a4 = (const float4*)sh;
#pragma unroll
            for (int m = 0; m < 8; ++m) acc = fma4(wA[m], a4[base + m], acc);
#pragma unroll
            for (int m = 0; m < 8; ++m) acc = fma4(wA[8 + m], a4[64 + base + m], acc);
            acc += __shfl_xor(acc, 1); acc += __shfl_xor(acc, 2); acc += __shfl_xor(acc, 4);
            float gf = __shfl(acc, b32 + 8);
            float gg = __shfl(acc, b32 + 16);
            float go = __shfl(acc, b32 + 24);
            if ((wlane & 31) == 0) {
                float cn = sigm(gf) * creg + sigm(acc) * tanh_(gg);
                creg = cn;
                tagstore(Hown + (t + 1) * 256 + u, sigm(go) * tanh_(cn), t + 2);
            }
            __syncthreads();
        }
    }
}

// WS[t][j] = sum_k att_W[j][k] h2[t][k]
__global__ __launch_bounds__(256) void ws_kernel(float* __restrict__ wsf)
{
    const int tid = threadIdx.x;
    const int t0 = blockIdx.x * 4;
    const uint2* H2 = (const uint2*)(wsf + F_H2A);
    const float* AWT = wsf + F_AWT;
    float* WS = wsf + F_WS;
    __shared__ float h2s[4][256];
#pragma unroll
    for (int q = 0; q < 4; ++q)
        h2s[q][tid] = __uint_as_float(H2[(t0 + q + 1) * 256 + tid].x);
    __syncthreads();
    float a0 = 0.f, a1 = 0.f, a2 = 0.f, a3 = 0.f;
#pragma unroll 4
    for (int k2 = 0; k2 < 256; ++k2) {
        float w = AWT[k2 * 256 + tid];
        a0 = fmaf(w, h2s[0][k2], a0); a1 = fmaf(w, h2s[1][k2], a1);
        a2 = fmaf(w, h2s[2][k2], a2); a3 = fmaf(w, h2s[3][k2], a3);
    }
    WS[(t0 + 0) * 256 + tid] = a0;
    WS[(t0 + 1) * 256 + tid] = a1;
    WS[(t0 + 2) * 256 + tid] = a2;
    WS[(t0 + 3) * 256 + tid] = a3;
}

// Per (t-tile 8, s-tile 128): e, exp, per-tile sums, ctx partials (no atomics).
__global__ __launch_bounds__(256) void att_kernel(
    const float* __restrict__ av, const float* __restrict__ enc,
    float* __restrict__ wsf)
{
    const int tid = threadIdx.x;
    const int t0 = blockIdx.x * 8, s0 = blockIdx.y * 128, by = blockIdx.y;
    const float* VB = wsf + F_VB;
    const float* WS = wsf + F_WS;
    float* SUMEP = wsf + F_SUMEP;
    float* CTXP  = wsf + F_CTXP;
    __shared__ float vbt[256][65];   // transposed VB half-tile [k][s]
    __shared__ float wss[8][256];
    __shared__ float avs[256];
    __shared__ float exs[8][64];
    __shared__ float ssum[8];
    avs[tid] = av[tid];
#pragma unroll
    for (int r = 0; r < 8; ++r) wss[r][tid] = WS[(t0 + r) * 256 + tid];
    if (tid < 8) ssum[tid] = 0.f;
    const int sidx = tid & 63, tq = tid >> 6;
    float ca[8] = {0.f, 0.f, 0.f, 0.f, 0.f, 0.f, 0.f, 0.f};
#pragma unroll
    for (int hf = 0; hf < 2; ++hf) {
        const int sb = s0 + hf * 64;
        __syncthreads();
#pragma unroll 4
        for (int r = 0; r < 64; ++r) vbt[tid][r] = VB[(sb + r) * 256 + tid];
        __syncthreads();
#pragma unroll
        for (int pass = 0; pass < 2; ++pass) {
            const int tl = tq + 4 * pass;
            float e = 0.f;
#pragma unroll 4
            for (int k2 = 0; k2 < 256; ++k2)
                e = fmaf(avs[k2], tanh_(wss[tl][k2] + vbt[k2][sidx]), e);
            float ex = __expf(e);    // |e| bounded: no max-shift needed
            exs[tl][sidx] = ex;
            float s = ex;
            s += __shfl_xor(s, 1);  s += __shfl_xor(s, 2);  s += __shfl_xor(s, 4);
            s += __shfl_xor(s, 8);  s += __shfl_xor(s, 16); s += __shfl_xor(s, 32);
            if (sidx == 0) ssum[tl] += s;
        }
        __syncthreads();
#pragma unroll 2
        for (int sl = 0; sl < 64; ++sl) {
            float ev = enc[(sb + sl) * 256 + tid];
#pragma unroll
            for (int r = 0; r < 8; ++r) ca[r] = fmaf(exs[r][sl], ev, ca[r]);
        }
    }
    __syncthreads();
    if (tid < 8) SUMEP[(t0 + tid) * 8 + by] = ssum[tid];
#pragma unroll
    for (int r = 0; r < 8; ++r)
        CTXP[by * 65536 + (t0 + r) * 256 + tid] = ca[r];
}

// O1[t][j] = relu(b1[j] + W1[j][:] . [h2[t], ctx[t]/sum[t]])
__global__ __launch_bounds__(256) void mlp1_kernel(
    const float* __restrict__ b1, float* __restrict__ wsf)
{
    const int tid = threadIdx.x;
    const int t0 = blockIdx.x * 4;
    const uint2* H2 = (const uint2*)(wsf + F_H2A);
    const float* CTXP = wsf + F_CTXP;
    const float* SUMEP = wsf + F_SUMEP;
    const float* W1T = wsf + F_W1T;
    float* O1 = wsf + F_O1;
    __shared__ __align__(16) float cat4[4][512];
    __shared__ float rs[4];
    if (tid < 4) {
        float s = 0.f;
#pragma unroll
        for (int i = 0; i < 8; ++i) s += SUMEP[(t0 + tid) * 8 + i];
        rs[tid] = 1.0f / s;
    }
    __syncthreads();
#pragma unroll
    for (int r = 0; r < 8; ++r) {
        int idx = r * 256 + tid;
        int tl = idx >> 9, j = idx & 511;
        float v;
        if (j < 256) v = __uint_as_float(H2[(t0 + tl + 1) * 256 + j].x);
        else {
            float s = 0.f;
#pragma unroll
            for (int p = 0; p < 8; ++p) s += CTXP[p * 65536 + (t0 + tl) * 256 + (j - 256)];
            v = s * rs[tl];
        }
        cat4[tl][j] = v;
    }
    __syncthreads();
    float a0 = 0.f, a1 = 0.f, a2 = 0.f, a3 = 0.f;
    float bv = b1[tid];
#pragma unroll 4
    for (int k2 = 0; k2 < 512; ++k2) {
        float w = W1T[k2 * 256 + tid];
        a0 = fmaf(w, cat4[0][k2], a0); a1 = fmaf(w, cat4[1][k2], a1);
        a2 = fmaf(w, cat4[2][k2], a2); a3 = fmaf(w, cat4[3][k2], a3);
    }
    O1[(t0 + 0) * 256 + tid] = fmaxf(bv + a0, 0.f);
    O1[(t0 + 1) * 256 + tid] = fmaxf(bv + a1, 0.f);
    O1[(t0 + 2) * 256 + tid] = fmaxf(bv + a2, 0.f);
    O1[(t0 + 3) * 256 + tid] = fmaxf(bv + a3, 0.f);
}

// fused mlp2 (relu) + mlp3 head
__global__ __launch_bounds__(256) void mlp23_kernel(
    const float* __restrict__ b2, const float* __restrict__ b3,
    float* __restrict__ wsf, float* __restrict__ out)
{
    const int tid = threadIdx.x;
    const int t0 = blockIdx.x * 4;
    const float* O1 = wsf + F_O1;
    const float* W2T = wsf + F_W2T;
    const float* W3T = wsf + F_W3T;
    __shared__ float v1s[4][256];
    __shared__ float v2s[4][256];
#pragma unroll
    for (int q = 0; q < 4; ++q) v1s[q][tid] = O1[(t0 + q) * 256 + tid];
    __syncthreads();
    float a0 = 0.f, a1 = 0.f, a2 = 0.f, a3 = 0.f;
    float bv = b2[tid];
#pragma unroll 4
    for (int k2 = 0; k2 < 256; ++k2) {
        float w = W2T[k2 * 256 + tid];
        a0 = fmaf(w, v1s[0][k2], a0); a1 = fmaf(w, v1s[1][k2], a1);
        a2 = fmaf(w, v1s[2][k2], a2); a3 = fmaf(w, v1s[3][k2], a3);
    }
    v2s[0][tid] = fmaxf(bv + a0, 0.f);
    v2s[1][tid] = fmaxf(bv + a1, 0.f);
    v2s[2][tid] = fmaxf(bv + a2, 0.f);
    v2s[3][tid] = fmaxf(bv + a3, 0.f);
    __syncthreads();
    if (tid < 4 * VOCAB) {
        const int tl = tid / VOCAB, j = tid % VOCAB;
        float m0 = 0.f, m1 = 0.f;
#pragma unroll 4
        for (int k2 = 0; k2 < 256; k2 += 2) {
            m0 = fmaf(W3T[k2 * VOCAB + j], v2s[tl][k2], m0);
            m1 = fmaf(W3T[(k2 + 1) * VOCAB + j], v2s[tl][k2 + 1], m1);
        }
        out[(t0 + tl) * VOCAB + j] = b3[j] + m0 + m1;
    }
}

extern "C" void kernel_launch(void* const* d_in, const int* in_sizes, int n_in,
                              void* d_out, int out_size, void* d_ws, size_t ws_size,
                              hipStream_t stream)
{
    (void)in_sizes; (void)n_in; (void)out_size; (void)ws_size;
    const int*   Y    = (const int*)  d_in[0];
    const float* h    = (const float*)d_in[1];
    const float* c    = (const float*)d_in[2];
    const float* enc  = (const float*)d_in[3];
    const float* emb  = (const float*)d_in[4];
    const float* Wih1 = (const float*)d_in[5];
    const float* Whh1 = (const float*)d_in[6];
    const float* bih1 = (const float*)d_in[7];
    const float* bhh1 = (const float*)d_in[8];
    const float* Wih2 = (const float*)d_in[9];
    const float* Whh2 = (const float*)d_in[10];
    const float* bih2 = (const float*)d_in[11];
    const float* bhh2 = (const float*)d_in[12];
    const float* Wih3 = (const float*)d_in[13];
    const float* Whh3 = (const float*)d_in[14];
    const float* bih3 = (const float*)d_in[15];
    const float* bhh3 = (const float*)d_in[16];
    const float* av   = (const float*)d_in[17];
    const float* attW = (const float*)d_in[18];
    const float* attV = (const float*)d_in[19];
    const float* attB = (const float*)d_in[20];
    const float* w1   = (const float*)d_in[21];
    const float* b1   = (const float*)d_in[22];
    const float* w2   = (const float*)d_in[23];
    const float* b2   = (const float*)d_in[24];
    const float* w3   = (const float*)d_in[25];
    const float* b3   = (const float*)d_in[26];
    float* wsf = (float*)d_ws;
    float* out = (float*)d_out;

    // prologue (loop-invariant precompute)
    rowdot_kernel<<<dim3(16, 16), 256, 0, stream>>>(emb, Y, Wih1, bih1, bhh1, wsf + F_X1, 1024);
    rowdot_kernel<<<dim3(64, 4),  256, 0, stream>>>(enc, nullptr, attV, attB, nullptr, wsf + F_VB, 256);
    transpose_kernel<<<dim3(16, 8), dim3(32, 8), 0, stream>>>(w1,   wsf + F_W1T, 256, 512);
    transpose_kernel<<<dim3(8, 8),  dim3(32, 8), 0, stream>>>(w2,   wsf + F_W2T, 256, 256);
    transpose_kernel<<<dim3(8, 2),  dim3(32, 8), 0, stream>>>(w3,   wsf + F_W3T, VOCAB, 256);
    transpose_kernel<<<dim3(8, 8),  dim3(32, 8), 0, stream>>>(attW, wsf + F_AWT, 256, 256);
    init_kernel<<<1, 256, 0, stream>>>(h, wsf);

    // barrier-free pipelined recurrence
    recurrence_kernel<<<NWGR, 512, 0, stream>>>(Whh1, Wih2, Whh2, Wih3, Whh3,
                                                bih2, bhh2, bih3, bhh3, c, wsf);

    // batch-parallel attention + MLP over all 256 steps
    ws_kernel<<<64, 256, 0, stream>>>(wsf);
    att_kernel<<<dim3(32, 8), 256, 0, stream>>>(av, enc, wsf);
    mlp1_kernel<<<64, 256, 0, stream>>>(b1, wsf);
    mlp23_kernel<<<64, 256, 0, stream>>>(b2, b3, wsf, out);
}

// Round 4
// 602.764 us; speedup vs baseline: 14.2439x; 1.4880x over previous
//
#include <hip/hip_runtime.h>

// ---------------------------------------------------------------------------
// DecoderRNN: 256-step LSTM(3) + Bahdanau attention + MLP head, batch=1.
// Round 4: ONE mega-kernel = 40 recurrence WGs (tagged-handoff pipeline,
// bank-conflict-free fragments, x-gemv off critical path) + 216 tail WGs
// (per-t attention+MLP, overlapped with recurrence via h2 tag polling).
// Prologue merged into a single prep kernel. 2 launches total.
// ---------------------------------------------------------------------------

#define VOCAB  47
#define NSTEP  256
#define NREC   40
#define NTAIL  216
#define NMEGA  (NREC + NTAIL)

typedef unsigned long long u64;

// workspace layout (float offsets)
#define F_H0A 64                         // u64 [257][256] tagged h0 history
#define F_H1A (F_H0A + 131584)           // u64 [257][256]
#define F_H2A (F_H1A + 131584)           // u64 [257][256]
#define F_X1  (F_H2A + 131584)           // [256][1024] precomputed L1 input gates
#define F_VB  (F_X1 + 262144)            // [1024][256] att_V@encT + att_b
#define F_W1T (F_VB + 262144)            // [512][256]
#define F_W2T (F_W1T + 131072)           // [256][256]
#define F_W3T (F_W2T + 65536)            // [256][47]
#define F_AWT (F_W3T + 12032)            // [256][256] att_W transposed

// mega-kernel LDS carve (floats)
#define R_SHH 0                          // [2][256] own-h double buffer
#define R_SHX 512                        // [2][256] upstream-x double buffer
#define T_H2  0                          // [256]
#define T_WS  256                        // [256]
#define T_WSP 512                        // [2][256] partial pairs
#define T_EX  1024                       // [1024]
#define T_CAT 2048                       // [512]
#define T_O1  2560                       // [256]
#define T_O2  2816                       // [256]
#define T_AV  3072                       // [256]
#define T_RED 3328                       // [16]

__device__ __forceinline__ float fma4(float4 w, float4 h, float acc) {
    acc = fmaf(w.x, h.x, acc); acc = fmaf(w.y, h.y, acc);
    acc = fmaf(w.z, h.z, acc); acc = fmaf(w.w, h.w, acc);
    return acc;
}
__device__ __forceinline__ float sigm(float x) {
    return __builtin_amdgcn_rcpf(1.f + __expf(-x));
}
__device__ __forceinline__ float tanh_(float x) {
    float e = __expf(2.f * x);
    return 1.f - 2.f * __builtin_amdgcn_rcpf(e + 1.f);
}

// tagged uncached handoff: 8B atom {tag<<32 | float bits}, relaxed agent scope
__device__ __forceinline__ void tagstore(u64* p, float v, unsigned tag) {
    u64 pk = ((u64)tag << 32) | (u64)__float_as_uint(v);
    __hip_atomic_store(p, pk, __ATOMIC_RELAXED, __HIP_MEMORY_SCOPE_AGENT);
}
__device__ __forceinline__ float pollval(u64* p, unsigned tag) {
    u64 v;
    do { v = __hip_atomic_load(p, __ATOMIC_RELAXED, __HIP_MEMORY_SCOPE_AGENT); }
    while ((unsigned)(v >> 32) != tag);
    return __uint_as_float((unsigned)(v & 0xffffffffull));
}
__device__ __forceinline__ float pollval_slow(u64* p, unsigned tag) {
    u64 v;
    for (;;) {
        v = __hip_atomic_load(p, __ATOMIC_RELAXED, __HIP_MEMORY_SCOPE_AGENT);
        if ((unsigned)(v >> 32) == tag) break;
        __builtin_amdgcn_s_sleep(2);
    }
    return __uint_as_float((unsigned)(v & 0xffffffffull));
}

// ---------------------------------------------------------------------------
// prep kernel: X1 rowdot, VB rowdot, 4 transposes, tag-init — by block range
// ---------------------------------------------------------------------------
__global__ __launch_bounds__(256) void prep_kernel(
    const float* __restrict__ emb, const int* __restrict__ Y,
    const float* __restrict__ Wih1, const float* __restrict__ bih1,
    const float* __restrict__ bhh1,
    const float* __restrict__ enc, const float* __restrict__ attV,
    const float* __restrict__ attB,
    const float* __restrict__ w1, const float* __restrict__ w2,
    const float* __restrict__ w3, const float* __restrict__ attW,
    const float* __restrict__ h, float* __restrict__ wsf)
{
    __shared__ __align__(16) float psm[4160];
    const int id = blockIdx.x, tid = threadIdx.x;

    if (id < 512) {
        // rowdot: OUT[r*C+c] = bias1[c](+bias2[c]) + dot(Arows[idx?idx[r]:r], Brows[c])
        const float* Arows; const int* idx; const float* Brows;
        const float* bias1; const float* bias2; float* out; int C, rt, ct;
        if (id < 256) {
            Arows = emb; idx = Y; Brows = Wih1; bias1 = bih1; bias2 = bhh1;
            out = wsf + F_X1; C = 1024; rt = id & 15; ct = id >> 4;
        } else {
            Arows = enc; idx = nullptr; Brows = attV; bias1 = attB; bias2 = nullptr;
            out = wsf + F_VB; C = 256; rt = (id - 256) & 63; ct = (id - 256) >> 6;
        }
        float* sA = psm;                      // [16][260]
        const int rl = tid >> 4, l = tid & 15;
        const int r = rt * 16 + rl;
        const int cb = ct * 64;
        const int arow = idx ? idx[r] : r;
        const float* Ap = Arows + arow * 256;
#pragma unroll
        for (int q = 0; q < 4; ++q)
            *(float4*)(&sA[rl * 260 + l * 16 + 4 * q]) = *(const float4*)(Ap + l * 16 + 4 * q);
        __syncthreads();
        for (int cc = 0; cc < 64; ++cc) {
            const int c = cb + cc;
            const float* Bp = Brows + c * 256;
            float acc = 0.f;
#pragma unroll
            for (int q = 0; q < 4; ++q) {
                float4 b = *(const float4*)(Bp + l * 4 + 64 * q);
                float4 a = *(const float4*)(&sA[rl * 260 + l * 4 + 64 * q]);
                acc = fma4(b, a, acc);
            }
            acc += __shfl_xor(acc, 1); acc += __shfl_xor(acc, 2);
            acc += __shfl_xor(acc, 4); acc += __shfl_xor(acc, 8);
            if (l == 0) {
                float bb = bias1[c] + (bias2 ? bias2[c] : 0.f);
                out[(size_t)r * C + c] = acc + bb;
            }
        }
    } else if (id < 784) {
        // transpose: out[c*rows + r] = in[r*cols + c]
        const float* in; float* out; int rows, cols, bxi, byi;
        if (id < 640)      { in = w1;   out = wsf + F_W1T; rows = 256; cols = 512;
                             bxi = (id - 512) & 15; byi = (id - 512) >> 4; }
        else if (id < 704) { in = w2;   out = wsf + F_W2T; rows = 256; cols = 256;
                             bxi = (id - 640) & 7;  byi = (id - 640) >> 3; }
        else if (id < 720) { in = w3;   out = wsf + F_W3T; rows = VOCAB; cols = 256;
                             bxi = (id - 704) & 7;  byi = (id - 704) >> 3; }
        else               { in = attW; out = wsf + F_AWT; rows = 256; cols = 256;
                             bxi = (id - 720) & 7;  byi = (id - 720) >> 3; }
        float* tile = psm;                    // [32][33]
        const int tx = tid & 31, ty = tid >> 5;
        const int bx = bxi * 32, by = byi * 32;
        int x = bx + tx;
#pragma unroll
        for (int j = ty; j < 32; j += 8) {
            int y = by + j;
            if (x < cols && y < rows) tile[j * 33 + tx] = in[y * cols + x];
        }
        __syncthreads();
        x = by + tx;
#pragma unroll
        for (int j = ty; j < 32; j += 8) {
            int y = bx + j;
            if (x < rows && y < cols) out[y * rows + x] = tile[tx * 33 + j];
        }
    } else {
        // init: row 0 of each tagged h array, tag 1
        tagstore((u64*)(wsf + F_H0A) + tid, h[tid],       1u);
        tagstore((u64*)(wsf + F_H1A) + tid, h[256 + tid], 1u);
        tagstore((u64*)(wsf + F_H2A) + tid, h[512 + tid], 1u);
    }
}

// ---------------------------------------------------------------------------
// mega kernel: WGs 0..7 L1, 8..23 L2, 24..39 L3, 40..255 tail (per-t att+MLP)
// ---------------------------------------------------------------------------
__global__ __launch_bounds__(512) void mega_kernel(
    const float* __restrict__ Whh1,
    const float* __restrict__ Wih2, const float* __restrict__ Whh2,
    const float* __restrict__ Wih3, const float* __restrict__ Whh3,
    const float* __restrict__ bih2, const float* __restrict__ bhh2,
    const float* __restrict__ bih3, const float* __restrict__ bhh3,
    const float* __restrict__ cin,  const float* __restrict__ av,
    const float* __restrict__ enc,
    const float* __restrict__ b1, const float* __restrict__ b2,
    const float* __restrict__ b3,
    float* __restrict__ wsf, float* __restrict__ out)
{
    __shared__ __align__(16) float smem[3456];
    const int tid = threadIdx.x, wg = blockIdx.x;
    const int wave = tid >> 6, wlane = tid & 63;

    u64* H0A = (u64*)(wsf + F_H0A);
    u64* H1A = (u64*)(wsf + F_H1A);
    u64* H2A = (u64*)(wsf + F_H2A);

    if (wg < 8) {
        // ---------------- L1: 8 WGs, 32 units each, 4 lanes per gate-row ----
        const float* X1 = wsf + F_X1;
        const int ug = wlane >> 4, gate = (wlane >> 2) & 3, l4 = wlane & 3;
        const int u = wg * 32 + wave * 4 + ug;
        const int ju = gate * 256 + u;
        float4 wA[16];
        const float* wp = Whh1 + ju * 256;
#pragma unroll
        for (int m = 0; m < 16; ++m) wA[m] = *(const float4*)(wp + (m * 4 + l4) * 4);
        float creg = ((wlane & 15) == 0) ? cin[u] : 0.f;
        const int b16 = wlane & 48;

        float xv = (l4 == 0) ? X1[ju] : 0.f;       // t = 0
        for (int t = 0; t < NSTEP; ++t) {
            if (tid < 256)
                smem[R_SHH + (t & 1) * 256 + tid] = pollval(H0A + t * 256 + tid, t + 1);
            __syncthreads();
            const float4* a4 = (const float4*)(smem + R_SHH + (t & 1) * 256);
            float acc = xv;
#pragma unroll
            for (int m = 0; m < 16; ++m) acc = fma4(wA[m], a4[m * 4 + l4], acc);
            acc += __shfl_xor(acc, 1); acc += __shfl_xor(acc, 2);
            float gf = __shfl(acc, b16 + 4);
            float gg = __shfl(acc, b16 + 8);
            float go = __shfl(acc, b16 + 12);
            if ((wlane & 15) == 0) {
                float cn = sigm(gf) * creg + sigm(acc) * tanh_(gg);
                creg = cn;
                tagstore(H0A + (t + 1) * 256 + u, sigm(go) * tanh_(cn), t + 2);
            }
            if (t < NSTEP - 1) xv = (l4 == 0) ? X1[(t + 1) * 1024 + ju] : 0.f;
        }
    } else if (wg < NREC) {
        // ---------------- L2 / L3: 16 WGs each, 16 units, 8 lanes per row ---
        const int role = (wg < 24) ? 1 : 2;
        const int ug = wlane >> 5, gate = (wlane >> 3) & 3, l8 = wlane & 7;
        const int wgr = wg - (role == 1 ? 8 : 24);
        const int u = wgr * 16 + wave * 2 + ug;
        const int ju = gate * 256 + u;
        const float* Wi = (role == 1) ? Wih2 : Wih3;
        const float* Wh = (role == 1) ? Whh2 : Whh3;
        float4 wAi[8], wAh[8];
        const float* wip = Wi + ju * 256;
        const float* whp = Wh + ju * 256;
#pragma unroll
        for (int m = 0; m < 8; ++m) {
            wAi[m] = *(const float4*)(wip + (m * 8 + l8) * 4);
            wAh[m] = *(const float4*)(whp + (m * 8 + l8) * 4);
        }
        float biasr = (l8 == 0)
            ? ((role == 1) ? (bih2[ju] + bhh2[ju]) : (bih3[ju] + bhh3[ju])) : 0.f;
        float creg = ((wlane & 31) == 0) ? cin[((role == 1) ? 256 : 512) + u] : 0.f;
        u64* Hup  = (role == 1) ? H0A : H1A;
        u64* Hown = (role == 1) ? H1A : H2A;
        const int b32 = wlane & 32;

        // prologue: xacc for t=0 from upstream h[1] (tag 2)
        if (tid < 256) smem[R_SHX + tid] = pollval(Hup + 256 + tid, 2);
        __syncthreads();
        float xacc;
        {
            const float4* x4 = (const float4*)(smem + R_SHX);
            float a = 0.f;
#pragma unroll
            for (int m = 0; m < 8; ++m) a = fma4(wAi[m], x4[m * 8 + l8], a);
            xacc = a;
        }

        for (int t = 0; t < NSTEP; ++t) {
            if (tid < 256)
                smem[R_SHH + (t & 1) * 256 + tid] = pollval(Hown + t * 256 + tid, t + 1);
            __syncthreads();
            const float4* h4 = (const float4*)(smem + R_SHH + (t & 1) * 256);
            float acc = xacc + biasr;
#pragma unroll
            for (int m = 0; m < 8; ++m) acc = fma4(wAh[m], h4[m * 8 + l8], acc);
            acc += __shfl_xor(acc, 1); acc += __shfl_xor(acc, 2); acc += __shfl_xor(acc, 4);
            float gf = __shfl(acc, b32 + 8);
            float gg = __shfl(acc, b32 + 16);
            float go = __shfl(acc, b32 + 24);
            if ((wlane & 31) == 0) {
                float cn = sigm(gf) * creg + sigm(acc) * tanh_(gg);
                creg = cn;
                tagstore(Hown + (t + 1) * 256 + u, sigm(go) * tanh_(cn), t + 2);
            }
            if (t < NSTEP - 1) {
                // off-critical-path: poll upstream h[t+2], accumulate Wih·x
                if (tid < 256)
                    smem[R_SHX + ((t + 1) & 1) * 256 + tid] =
                        pollval(Hup + (t + 2) * 256 + tid, t + 3);
                __syncthreads();
                const float4* x4 = (const float4*)(smem + R_SHX + ((t + 1) & 1) * 256);
                float a = 0.f;
#pragma unroll
                for (int m = 0; m < 8; ++m) a = fma4(wAi[m], x4[m * 8 + l8], a);
                xacc = a;
            }
        }
    } else {
        // ---------------- tail: per-t attention + MLP, overlapped -----------
        const float* VB  = wsf + F_VB;
        const float* W1T = wsf + F_W1T;
        const float* W2T = wsf + F_W2T;
        const float* W3T = wsf + F_W3T;
        const float* AWT = wsf + F_AWT;
        const int j = tid & 255, hf = tid >> 8;

        if (tid < 256) smem[T_AV + tid] = av[tid];

        for (int t = wg - NREC; t < NSTEP; t += NTAIL) {
            __syncthreads();
            // 1. h2[t] (stored at row t+1, tag t+2)
            if (tid < 256)
                smem[T_H2 + tid] = pollval_slow(H2A + (t + 1) * 256 + tid, t + 2);
            __syncthreads();
            // 2. ws[j] = sum_k AWT[k][j] h2[k]  (k split in halves)
            {
                const float* wp = AWT + (size_t)(hf * 128) * 256 + j;
                const float* hp = smem + T_H2 + hf * 128;
                float p0 = 0.f, p1 = 0.f;
#pragma unroll 4
                for (int k = 0; k < 128; k += 2) {
                    p0 = fmaf(wp[k * 256], hp[k], p0);
                    p1 = fmaf(wp[(k + 1) * 256], hp[k + 1], p1);
                }
                smem[T_WSP + hf * 256 + j] = p0 + p1;
            }
            __syncthreads();
            if (tid < 256) smem[T_WS + tid] = smem[T_WSP + tid] + smem[T_WSP + 256 + tid];
            __syncthreads();
            // 3. e + exp: 2 s-values per thread
            {
                const float* avs_ = smem + T_AV;
                const float* ws_  = smem + T_WS;
#pragma unroll
                for (int rep = 0; rep < 2; ++rep) {
                    const int s = tid + rep * 512;
                    const float4* vb4 = (const float4*)(VB + (size_t)s * 256);
                    float e0 = 0.f, e1 = 0.f, e2 = 0.f, e3 = 0.f;
#pragma unroll 4
                    for (int q = 0; q < 64; ++q) {
                        float4 vb = vb4[q];
                        const int k = q * 4;
                        e0 = fmaf(avs_[k],     tanh_(ws_[k]     + vb.x), e0);
                        e1 = fmaf(avs_[k + 1], tanh_(ws_[k + 1] + vb.y), e1);
                        e2 = fmaf(avs_[k + 2], tanh_(ws_[k + 2] + vb.z), e2);
                        e3 = fmaf(avs_[k + 3], tanh_(ws_[k + 3] + vb.w), e3);
                    }
                    smem[T_EX + s] = __expf((e0 + e1) + (e2 + e3));  // |e| bounded
                }
            }
            __syncthreads();
            // 4. softmax denom
            {
                float sv = smem[T_EX + tid] + smem[T_EX + 512 + tid];
                sv += __shfl_xor(sv, 1);  sv += __shfl_xor(sv, 2);
                sv += __shfl_xor(sv, 4);  sv += __shfl_xor(sv, 8);
                sv += __shfl_xor(sv, 16); sv += __shfl_xor(sv, 32);
                if (wlane == 0) smem[T_RED + wave] = sv;
            }
            __syncthreads();
            if (tid == 0) {
                float sm = 0.f;
#pragma unroll
                for (int i = 0; i < 8; ++i) sm += smem[T_RED + i];
                smem[T_RED + 8] = __builtin_amdgcn_rcpf(sm);
            }
            __syncthreads();
            // 5. ctx partial over s-half
            {
                const float* ex_ = smem + T_EX + hf * 512;
                const float* ep  = enc + (size_t)(hf * 512) * 256 + j;
                float c0 = 0.f, c1 = 0.f, c2 = 0.f, c3 = 0.f;
#pragma unroll 2
                for (int s = 0; s < 512; s += 4) {
                    c0 = fmaf(ex_[s],     ep[(size_t)s * 256],       c0);
                    c1 = fmaf(ex_[s + 1], ep[(size_t)(s + 1) * 256], c1);
                    c2 = fmaf(ex_[s + 2], ep[(size_t)(s + 2) * 256], c2);
                    c3 = fmaf(ex_[s + 3], ep[(size_t)(s + 3) * 256], c3);
                }
                smem[T_WSP + hf * 256 + j] = (c0 + c1) + (c2 + c3);
            }
            __syncthreads();
            // 6. cat = [h2, ctx/sum]
            if (tid < 256) {
                smem[T_CAT + tid] = smem[T_H2 + tid];
                smem[T_CAT + 256 + tid] =
                    (smem[T_WSP + tid] + smem[T_WSP + 256 + tid]) * smem[T_RED + 8];
            }
            __syncthreads();
            // 7. mlp1 (K=512, halves of 256)
            {
                const float* wp = W1T + (size_t)(hf * 256) * 256 + j;
                const float* cp = smem + T_CAT + hf * 256;
                float p0 = 0.f, p1 = 0.f;
#pragma unroll 4
                for (int k = 0; k < 256; k += 2) {
                    p0 = fmaf(wp[(size_t)k * 256], cp[k], p0);
                    p1 = fmaf(wp[(size_t)(k + 1) * 256], cp[k + 1], p1);
                }
                smem[T_WSP + hf * 256 + j] = p0 + p1;
            }
            __syncthreads();
            if (tid < 256)
                smem[T_O1 + tid] =
                    fmaxf(b1[tid] + smem[T_WSP + tid] + smem[T_WSP + 256 + tid], 0.f);
            __syncthreads();
            // 8. mlp2 (K=256, halves of 128)
            {
                const float* wp = W2T + (size_t)(hf * 128) * 256 + j;
                const float* cp = smem + T_O1 + hf * 128;
                float p0 = 0.f, p1 = 0.f;
#pragma unroll 4
                for (int k = 0; k < 128; k += 2) {
                    p0 = fmaf(wp[(size_t)k * 256], cp[k], p0);
                    p1 = fmaf(wp[(size_t)(k + 1) * 256], cp[k + 1], p1);
                }
                smem[T_WSP + hf * 256 + j] = p0 + p1;
            }
            __syncthreads();
            if (tid < 256)
                smem[T_O2 + tid] =
                    fmaxf(b2[tid] + smem[T_WSP + tid] + smem[T_WSP + 256 + tid], 0.f);
            __syncthreads();
            // 9. mlp3 head: 47 outputs × 8-lane k-split
            if (tid < 8 * VOCAB) {
                const int jj = tid >> 3, l = tid & 7;
                const float* wp = W3T + (size_t)(l * 32) * VOCAB + jj;
                const float* vp = smem + T_O2 + l * 32;
                float p = 0.f;
#pragma unroll 4
                for (int k = 0; k < 32; ++k) p = fmaf(wp[(size_t)k * VOCAB], vp[k], p);
                p += __shfl_xor(p, 1); p += __shfl_xor(p, 2); p += __shfl_xor(p, 4);
                if (l == 0) out[t * VOCAB + jj] = b3[jj] + p;
            }
        }
    }
}

extern "C" void kernel_launch(void* const* d_in, const int* in_sizes, int n_in,
                              void* d_out, int out_size, void* d_ws, size_t ws_size,
                              hipStream_t stream)
{
    (void)in_sizes; (void)n_in; (void)out_size; (void)ws_size;
    const int*   Y    = (const int*)  d_in[0];
    const float* h    = (const float*)d_in[1];
    const float* c    = (const float*)d_in[2];
    const float* enc  = (const float*)d_in[3];
    const float* emb  = (const float*)d_in[4];
    const float* Wih1 = (const float*)d_in[5];
    const float* Whh1 = (const float*)d_in[6];
    const float* bih1 = (const float*)d_in[7];
    const float* bhh1 = (const float*)d_in[8];
    const float* Wih2 = (const float*)d_in[9];
    const float* Whh2 = (const float*)d_in[10];
    const float* bih2 = (const float*)d_in[11];
    const float* bhh2 = (const float*)d_in[12];
    const float* Wih3 = (const float*)d_in[13];
    const float* Whh3 = (const float*)d_in[14];
    const float* bih3 = (const float*)d_in[15];
    const float* bhh3 = (const float*)d_in[16];
    const float* av   = (const float*)d_in[17];
    const float* attW = (const float*)d_in[18];
    const float* attV = (const float*)d_in[19];
    const float* attB = (const float*)d_in[20];
    const float* w1   = (const float*)d_in[21];
    const float* b1   = (const float*)d_in[22];
    const float* w2   = (const float*)d_in[23];
    const float* b2   = (const float*)d_in[24];
    const float* w3   = (const float*)d_in[25];
    const float* b3   = (const float*)d_in[26];
    float* wsf = (float*)d_ws;
    float* out = (float*)d_out;

    prep_kernel<<<785, 256, 0, stream>>>(emb, Y, Wih1, bih1, bhh1,
                                         enc, attV, attB,
                                         w1, w2, w3, attW, h, wsf);

    mega_kernel<<<NMEGA, 512, 0, stream>>>(Whh1, Wih2, Whh2, Wih3, Whh3,
                                           bih2, bhh2, bih3, bhh3,
                                           c, av, enc, b1, b2, b3, wsf, out);
}